// Round 12
// baseline (210.707 us; speedup 1.0000x reference)
//
#include <hip/hip_runtime.h>
#include <hip/hip_bf16.h>
#include <math.h>
#include <stdint.h>

#define N_ROWS 8192
#define DIM 512
#define INV_TAU 5.0f
#define EXP5 148.41315910257660342f   // exp(1/tau) = exp(5)

typedef float f32x16 __attribute__((ext_vector_type(16)));
typedef long long i64;

union PairU {            // one dwordx4 = two K16 units of one 32-row frag
  int4 v;
  struct { i64 lo, hi; } s;
};

__device__ __forceinline__ void gload_lds16(const void* g, void* l) {
  __builtin_amdgcn_global_load_lds(
      (__attribute__((address_space(1))) void*)(void*)g,
      (__attribute__((address_space(3))) void*)l,
      16, 0, 0);
}

// Block = 32 rows (one 32x32-MFMA group), 512 threads. Thread t: row t>>4,
// k-span (t&15)*32..+31. Norms via 16-lane butterfly, fp32 diag dot, fp8
// e4m3 quantization into the 32x32-fragment PAIR-PACKED layout:
//   unit (g32=row/32, k16=k/16): 512B, lane l holds row g32*32+(l&31),
//   k = k16*16 + (l>>5)*8 + 0..7. Pairs of adjacent k16 units interleave as
//   lane-major dwordx4 (lo=unit 2p, hi=unit 2p+1) -> 1024B per (g32,pair);
//   16 KB per 32-row group. One dwordx4 per lane covers K=32 of 32 rows.
// Scatter goes through LDS so global writes are coalesced int4.
// Also zeroes r1/r2/brow/bcol/out.
__global__ __launch_bounds__(512) void normalize_kernel(
    const float* __restrict__ z1, const float* __restrict__ z2,
    uint8_t* __restrict__ h1p, uint8_t* __restrict__ h2p,
    float* __restrict__ dvec,
    float* __restrict__ r1, float* __restrict__ r2,
    float* __restrict__ brow, float* __restrict__ bcol,
    float* __restrict__ out) {
  __shared__ __align__(16) uint8_t L[32768];  // 16KB h1-part, 16KB h2-part
  const int t = threadIdx.x;
  const int lr = t >> 4;          // row in group 0..31
  const int kb = t & 15;          // this thread's 32-elem k-block
  const int row = blockIdx.x * 32 + lr;
  const float4* p1 = (const float4*)(z1 + (size_t)row * DIM + kb * 32);
  const float4* p2 = (const float4*)(z2 + (size_t)row * DIM + kb * 32);
  float4 a[8], b[8];
  float s1 = 0.f, s2 = 0.f, s3 = 0.f;
#pragma unroll
  for (int i = 0; i < 8; i++) {
    a[i] = p1[i]; b[i] = p2[i];
    s1 += a[i].x*a[i].x + a[i].y*a[i].y + a[i].z*a[i].z + a[i].w*a[i].w;
    s2 += b[i].x*b[i].x + b[i].y*b[i].y + b[i].z*b[i].z + b[i].w*b[i].w;
    s3 += a[i].x*b[i].x + a[i].y*b[i].y + a[i].z*b[i].z + a[i].w*b[i].w;
  }
  // reduce across the 16 contiguous lanes sharing a row
  for (int m = 1; m <= 8; m <<= 1) {
    s1 += __shfl_xor(s1, m);
    s2 += __shfl_xor(s2, m);
    s3 += __shfl_xor(s3, m);
  }
  const float inv1 = 1.0f / fmaxf(sqrtf(s1), 1e-12f);
  const float inv2 = 1.0f / fmaxf(sqrtf(s2), 1e-12f);
  int w1[8], w2[8];
#pragma unroll
  for (int i = 0; i < 8; i++) {
    int wv = __builtin_amdgcn_cvt_pk_fp8_f32(a[i].x*inv1, a[i].y*inv1, 0, false);
    w1[i] = __builtin_amdgcn_cvt_pk_fp8_f32(a[i].z*inv1, a[i].w*inv1, wv, true);
    wv = __builtin_amdgcn_cvt_pk_fp8_f32(b[i].x*inv2, b[i].y*inv2, 0, false);
    w2[i] = __builtin_amdgcn_cvt_pk_fp8_f32(b[i].z*inv2, b[i].w*inv2, wv, true);
  }
  // 32x32 pair-packed LDS scatter. This thread's K=32 block is pair kb.
  // lane lr gets (w0,w1 | w4,w5); lane lr+32 gets (w2,w3 | w6,w7).
  *(int4*)(L + kb * 1024 + lr * 16)          = make_int4(w1[0], w1[1], w1[4], w1[5]);
  *(int4*)(L + kb * 1024 + (lr + 32) * 16)   = make_int4(w1[2], w1[3], w1[6], w1[7]);
  *(int4*)(L + 16384 + kb * 1024 + lr * 16)        = make_int4(w2[0], w2[1], w2[4], w2[5]);
  *(int4*)(L + 16384 + kb * 1024 + (lr + 32) * 16) = make_int4(w2[2], w2[3], w2[6], w2[7]);
  if (kb == 0) dvec[row] = s3 * inv1 * inv2;
  if (t < 32) {
    const int i = blockIdx.x * 32 + t;
    r1[i] = 0.f; r2[i] = 0.f; brow[i] = 0.f; bcol[i] = 0.f;
    if (i == 0) out[0] = 0.f;
  }
  __syncthreads();
  // coalesced write-out: one group's packed data is 16KB contiguous per array
  const size_t gb = (size_t)blockIdx.x * 16384;
  int4* g1 = (int4*)(h1p + gb);
  int4* g2 = (int4*)(h2p + gb);
  const int4* Lv = (const int4*)L;
  g1[t]        = Lv[t];
  g1[t + 512]  = Lv[t + 512];
  g2[t]        = Lv[t + 1024];
  g2[t + 512]  = Lv[t + 1536];
}

// Upper triangle of W W^T, W=[h1;h2] (16384 rows), 256x128 tiles, 512
// threads / 8 waves; wave w owns rows 32w..32w+31 x all 128 cols as a 1x4
// row of 32x32 MFMA tiles -> v_mfma_f32_32x32x16_fp8_fp8: per kbp (K=64)
// the loop issues the SAME 2 A-loads + 8 ds_read_b128 as r11 but only
// 16 MFMA (vs 32) — half the MFMA issue slots for the same FLOP.
// Triangle/quadrant decode identical to r11. B tile 64KB staged once
// (linear copy of 4 contiguous 16KB groups); A unique per wave, depth-3
// register pipeline, two anchored pointers (16KB span > 13-bit imm).
__global__ __launch_bounds__(512, 4) void expsum_kernel(
    const uint8_t* __restrict__ h1p, const uint8_t* __restrict__ h2p,
    float* __restrict__ r1, float* __restrict__ r2,
    float* __restrict__ brow, float* __restrict__ bcol) {
  __shared__ __align__(16) uint8_t Bs[65536];   // 64 KB B tile

  // 4160 = 8*520 blocks; XCD-stripe swizzle then decode u -> (bi,bj)
  const int u = (blockIdx.x & 7) * 520 + (blockIdx.x >> 3);
  int bi = (int)((129.0 - sqrt(129.0 * 129.0 - 4.0 * (double)u)) * 0.5);
  while (bi * (129 - bi) > u) bi--;
  while ((bi + 1) * (128 - bi) <= u) bi++;
  const int bj = 2 * bi + (u - bi * (129 - bi));
  const bool needPred = (bj == 2 * bi) || (bj == 2 * bi + 1);

  const uint8_t* Ap = (bi < 32) ? h1p : h2p;
  const uint8_t* Bp = (bj < 64) ? h1p : h2p;
  float* rowsOut = (bi < 32) ? ((bj < 64) ? r1 : brow) : r2;
  float* colsOut = (bj < 64) ? r1 : ((bi < 32) ? bcol : r2);
  const int iOutBase = (bi & 31) * 256;
  const int jOutBase = (bj & 63) * 128;
  const int giBase = bi * 256;   // W-space, for diagonal predication
  const int gjBase = bj * 128;

  const int t = threadIdx.x;
  const int w = t >> 6;         // wave 0..7: rows 32w..32w+31
  const int lane = t & 63;
  const int l32 = lane & 31;
  const int l5 = lane >> 5;

  // ---- A stream: one 32-row group per wave; 16 KB span -> two anchors ----
  const uint8_t* Ag =
      Ap + ((size_t)((bi & 31) * 8 + w)) * 16384 + (size_t)lane * 16;
  const uint8_t* aLo = Ag + 4096;    // pairs 0..7  : ofs pp*1024-4096
  const uint8_t* aHi = Ag + 12288;   // pairs 8..15 : ofs pp*1024-12288

  // A prefetch kbp=0,1 (pairs 0..3)
  PairU Ar[3][2];
#pragma unroll
  for (int p = 0; p < 4; p++)
    Ar[p >> 1][p & 1].v = *(const int4*)(aLo + p * 1024 - 4096);

  // ---- B staging: linear 64KB copy (4 contiguous packed groups) ----
  {
    const uint8_t* Bgp = Bp + (size_t)(bj & 63) * 65536;
#pragma unroll
    for (int rnd = 0; rnd < 8; rnd++)
      gload_lds16(Bgp + rnd * 8192 + t * 16, Bs + rnd * 8192 + t * 16);
  }

  f32x16 acc[4];
#pragma unroll
  for (int fn = 0; fn < 4; fn++)
#pragma unroll
    for (int r = 0; r < 16; r++) acc[fn][r] = 0.0f;

  const uint8_t* BsL = Bs + lane * 16;   // single VGPR base, all-imm offsets

  __syncthreads();   // B tile ready (also drains the A prefetch, fine)

#pragma unroll
  for (int kbp = 0; kbp < 8; kbp++) {
    const int cur = kbp % 3;
    if (kbp < 6) {
      const int nxt = (kbp + 2) % 3;
      const int pp0 = (kbp + 2) * 2;
#pragma unroll
      for (int j = 0; j < 2; j++) {
        const int pp = pp0 + j;
        Ar[nxt][j].v = (pp < 8)
            ? *(const int4*)(aLo + pp * 1024 - 4096)
            : *(const int4*)(aHi + pp * 1024 - 12288);
      }
    }
#pragma unroll
    for (int j = 0; j < 2; j++) {
      const int pp = kbp * 2 + j;
      PairU Bf[4];
#pragma unroll
      for (int fn = 0; fn < 4; fn++)
        Bf[fn].v = *(const int4*)(BsL + fn * 16384 + pp * 1024);
#pragma unroll
      for (int fn = 0; fn < 4; fn++)
        acc[fn] = __builtin_amdgcn_mfma_f32_32x32x16_fp8_fp8(
            Ar[cur][j].s.lo, Bf[fn].s.lo, acc[fn], 0, 0, 0);
#pragma unroll
      for (int fn = 0; fn < 4; fn++)
        acc[fn] = __builtin_amdgcn_mfma_f32_32x32x16_fp8_fp8(
            Ar[cur][j].s.hi, Bf[fn].s.hi, acc[fn], 0, 0, 0);
    }
  }

  // ---- Epilogue. 32x32 C/D layout: col = lane&31,
  //      row = 4*(lane>>5) + (reg&3) + 8*(reg>>2)  [m74/m101-verified] ----
  float rowp[16];
  float colp[4];
#pragma unroll
  for (int r = 0; r < 16; r++) rowp[r] = 0.0f;
#pragma unroll
  for (int fn = 0; fn < 4; fn++) colp[fn] = 0.0f;

  if (!needPred) {
#pragma unroll
    for (int fn = 0; fn < 4; fn++)
#pragma unroll
      for (int r = 0; r < 16; r++) {
        const float e = __expf(acc[fn][r] * INV_TAU);
        rowp[r] += e;
        colp[fn] += e;
      }
  } else {
    // diagonal-straddling: keep rows gi<=gj, cols gi<gj (W-space indices)
#pragma unroll
    for (int fn = 0; fn < 4; fn++)
#pragma unroll
      for (int r = 0; r < 16; r++) {
        const int gi = giBase + w * 32 + 4 * l5 + (r & 3) + 8 * (r >> 2);
        const int gj = gjBase + fn * 32 + l32;
        const float e = __expf(acc[fn][r] * INV_TAU);
        rowp[r] += (gi <= gj) ? e : 0.0f;
        colp[fn] += (gi < gj) ? e : 0.0f;
      }
  }

  // reduction buffers alias into Bs — safe after all waves left the K-loop
  __syncthreads();
  float* lds_col = (float*)Bs;          // 128 floats, contended -> zero+atomic
  float* lds_row = lds_col + 128;       // 256 floats, unique -> plain store
  if (t < 128) lds_col[t] = 0.0f;
  __syncthreads();

  // Row sums: reduce each reg across the 32 lanes sharing l5; lane l32==0 of
  // each half owns its 16 rows -> plain store (unique per (w,l5,r)).
#pragma unroll
  for (int r = 0; r < 16; r++) {
    float v = rowp[r];
    v += __shfl_xor(v, 1);
    v += __shfl_xor(v, 2);
    v += __shfl_xor(v, 4);
    v += __shfl_xor(v, 8);
    v += __shfl_xor(v, 16);
    if (l32 == 0) lds_row[w * 32 + 4 * l5 + (r & 3) + 8 * (r >> 2)] = v;
  }
  // Col sums: fold the two 32-lane halves; lanes 0..31 atomicAdd (8 waves).
#pragma unroll
  for (int fn = 0; fn < 4; fn++) {
    float v = colp[fn];
    v += __shfl_xor(v, 32);
    if (l5 == 0) atomicAdd(&lds_col[fn * 32 + l32], v);
  }
  __syncthreads();

  if (t < 256) atomicAdd(&rowsOut[iOutBase + t], lds_row[t]);
  else if (t < 384) atomicAdd(&colsOut[jOutBase + (t - 256)], lds_col[t - 256]);
}

__global__ __launch_bounds__(256) void finalize_kernel(
    const float* __restrict__ r1, const float* __restrict__ r2,
    const float* __restrict__ brow, const float* __restrict__ bcol,
    const float* __restrict__ dvec, float* __restrict__ out) {
  const int i = blockIdx.x * 256 + threadIdx.x;
  const float den1 = r1[i] + brow[i] - EXP5;
  const float den2 = r2[i] + bcol[i] - EXP5;
  float v = 0.5f * (logf(den1) + logf(den2)) - INV_TAU * dvec[i];
  for (int m = 32; m; m >>= 1) v += __shfl_xor(v, m);
  __shared__ float red[4];
  const int wave = threadIdx.x >> 6;
  if ((threadIdx.x & 63) == 0) red[wave] = v;
  __syncthreads();
  if (threadIdx.x == 0) atomicAdd(out, red[0] + red[1] + red[2] + red[3]);
}

extern "C" void kernel_launch(void* const* d_in, const int* in_sizes, int n_in,
                              void* d_out, int out_size, void* d_ws, size_t ws_size,
                              hipStream_t stream) {
  const float* z1 = (const float*)d_in[0];
  const float* z2 = (const float*)d_in[1];
  float* out = (float*)d_out;

  char* ws = (char*)d_ws;
  uint8_t* h1p = (uint8_t*)ws;                 // 4 MiB fp8 pair-packed (32x32)
  uint8_t* h2p = (uint8_t*)(ws + (4u << 20));  // 4 MiB
  float* r1   = (float*)(ws + (8u << 20));
  float* r2   = r1 + N_ROWS;
  float* brow = r2 + N_ROWS;
  float* bcol = brow + N_ROWS;
  float* dvec = bcol + N_ROWS;

  normalize_kernel<<<N_ROWS / 32, 512, 0, stream>>>(
      z1, z2, h1p, h2p, dvec, r1, r2, brow, bcol, out);
  expsum_kernel<<<4160, 512, 0, stream>>>(h1p, h2p, r1, r2, brow, bcol);
  finalize_kernel<<<N_ROWS / 256, 256, 0, stream>>>(r1, r2, brow, bcol, dvec, out);
}

// Round 13
// 207.972 us; speedup vs baseline: 1.0131x; 1.0131x over previous
//
#include <hip/hip_runtime.h>
#include <hip/hip_bf16.h>
#include <math.h>
#include <stdint.h>

#define N_ROWS 8192
#define DIM 512
#define INV_TAU 5.0f
#define EXP5 148.41315910257660342f   // exp(1/tau) = exp(5)

typedef float f32x4 __attribute__((ext_vector_type(4)));
typedef long long i64;

union PairU {            // one dwordx4 = two K-steps of one frag
  int4 v;
  struct { i64 lo, hi; } s;
};

__device__ __forceinline__ void gload_lds16(const void* g, void* l) {
  __builtin_amdgcn_global_load_lds(
      (__attribute__((address_space(1))) void*)(void*)g,
      (__attribute__((address_space(3))) void*)l,
      16, 0, 0);
}

// Block = 16 rows (one MFMA group). Thread t: row t>>4, k-span (t&15)*32..+31.
// Norms via 16-lane butterfly, fp32 diag dot, fp8 e4m3 quantization into the
// PAIR-PACKED fragment layout:
//   hp[g=row/16][kbp=k/64][lane][p]  (lane l: row l&15, k-quarter l>>4;
//   p in {0,1} selects kb=2*kbp+p; 1024B per (g,kbp)).
// Scatter goes through LDS so global writes are coalesced int4.
// Also zeroes r1/r2/brow/bcol/out.
__global__ __launch_bounds__(256) void normalize_kernel(
    const float* __restrict__ z1, const float* __restrict__ z2,
    uint8_t* __restrict__ h1p, uint8_t* __restrict__ h2p,
    float* __restrict__ dvec,
    float* __restrict__ r1, float* __restrict__ r2,
    float* __restrict__ brow, float* __restrict__ bcol,
    float* __restrict__ out) {
  __shared__ __align__(16) uint8_t L[16384];  // 8KB h1-part, 8KB h2-part
  const int t = threadIdx.x;
  const int lr = t >> 4;          // row in group 0..15
  const int kb = t & 15;          // this thread's 32-elem k-block
  const int row = blockIdx.x * 16 + lr;
  const float4* p1 = (const float4*)(z1 + (size_t)row * DIM + kb * 32);
  const float4* p2 = (const float4*)(z2 + (size_t)row * DIM + kb * 32);
  float4 a[8], b[8];
  float s1 = 0.f, s2 = 0.f, s3 = 0.f;
#pragma unroll
  for (int i = 0; i < 8; i++) {
    a[i] = p1[i]; b[i] = p2[i];
    s1 += a[i].x*a[i].x + a[i].y*a[i].y + a[i].z*a[i].z + a[i].w*a[i].w;
    s2 += b[i].x*b[i].x + b[i].y*b[i].y + b[i].z*b[i].z + b[i].w*b[i].w;
    s3 += a[i].x*b[i].x + a[i].y*b[i].y + a[i].z*b[i].z + a[i].w*b[i].w;
  }
  for (int m = 1; m <= 8; m <<= 1) {
    s1 += __shfl_xor(s1, m);
    s2 += __shfl_xor(s2, m);
    s3 += __shfl_xor(s3, m);
  }
  const float inv1 = 1.0f / fmaxf(sqrtf(s1), 1e-12f);
  const float inv2 = 1.0f / fmaxf(sqrtf(s2), 1e-12f);
  int w1[8], w2[8];
#pragma unroll
  for (int i = 0; i < 8; i++) {
    int w = __builtin_amdgcn_cvt_pk_fp8_f32(a[i].x*inv1, a[i].y*inv1, 0, false);
    w1[i] = __builtin_amdgcn_cvt_pk_fp8_f32(a[i].z*inv1, a[i].w*inv1, w, true);
    w = __builtin_amdgcn_cvt_pk_fp8_f32(b[i].x*inv2, b[i].y*inv2, 0, false);
    w2[i] = __builtin_amdgcn_cvt_pk_fp8_f32(b[i].z*inv2, b[i].w*inv2, w, true);
  }
  // pair-packed LDS scatter: byte = (kb>>1)*1024 + q*256 + lr*16 + (kb&1)*8
  union { i64 q; int d[2]; } u;
  const int lbase = (kb >> 1) * 1024 + lr * 16 + (kb & 1) * 8;
#pragma unroll
  for (int q = 0; q < 4; q++) {
    u.d[0] = w1[q*2]; u.d[1] = w1[q*2+1];
    *(i64*)(L + lbase + q * 256) = u.q;
    u.d[0] = w2[q*2]; u.d[1] = w2[q*2+1];
    *(i64*)(L + 8192 + lbase + q * 256) = u.q;
  }
  if (kb == 0) dvec[row] = s3 * inv1 * inv2;
  if (t < 16) {
    const int i = blockIdx.x * 16 + t;
    r1[i] = 0.f; r2[i] = 0.f; brow[i] = 0.f; bcol[i] = 0.f;
    if (i == 0) out[0] = 0.f;
  }
  __syncthreads();
  const size_t gb = (size_t)blockIdx.x * 8192;
  int4* g1 = (int4*)(h1p + gb);
  int4* g2 = (int4*)(h2p + gb);
  const int4* Lv = (const int4*)L;
  g1[t]       = Lv[t];
  g1[t + 256] = Lv[t + 256];
  g2[t]       = Lv[t + 512];
  g2[t + 256] = Lv[t + 768];
}

// Upper triangle of W W^T, W=[h1;h2] (16384 rows), 256x128 tiles, 512
// threads / 8 waves; wave w owns rows 32w..32w+31 x 128 cols (2x8 frags of
// 16x16x32 fp8 MFMA) — r11 config. NEW vs r11: B is register
// DOUBLE-BUFFERED — each kbp issues the 8 ds_read_b128 for kbp+1 and runs
// its 16 MFMAs on registers loaded one full iteration earlier, so the
// K-loop has no blocking lgkm wait (A already depth-3 on vmcnt). Ping-pong
// Bbuf[2][8] with full unroll -> static indices, no register copies.
__global__ __launch_bounds__(512, 4) void expsum_kernel(
    const uint8_t* __restrict__ h1p, const uint8_t* __restrict__ h2p,
    float* __restrict__ r1, float* __restrict__ r2,
    float* __restrict__ brow, float* __restrict__ bcol) {
  __shared__ __align__(16) uint8_t Bs[65536];   // 64 KB B tile

  // 4160 = 8*520 blocks; XCD-stripe swizzle then decode u -> (bi,bj)
  const int u = (blockIdx.x & 7) * 520 + (blockIdx.x >> 3);
  int bi = (int)((129.0 - sqrt(129.0 * 129.0 - 4.0 * (double)u)) * 0.5);
  while (bi * (129 - bi) > u) bi--;
  while ((bi + 1) * (128 - bi) <= u) bi++;
  const int bj = 2 * bi + (u - bi * (129 - bi));
  const bool needPred = (bj == 2 * bi) || (bj == 2 * bi + 1);

  const uint8_t* Ap = (bi < 32) ? h1p : h2p;
  const uint8_t* Bp = (bj < 64) ? h1p : h2p;
  float* rowsOut = (bi < 32) ? ((bj < 64) ? r1 : brow) : r2;
  float* colsOut = (bj < 64) ? r1 : ((bi < 32) ? bcol : r2);
  const int iOutBase = (bi & 31) * 256;
  const int jOutBase = (bj & 63) * 128;
  const int giBase = bi * 256;   // W-space, for diagonal predication
  const int gjBase = bj * 128;

  const int t = threadIdx.x;
  const int w = t >> 6;         // wave 0..7: rows 32w..32w+31
  const int lane = t & 63;
  const int l16 = lane & 15;
  const int kq = lane >> 4;     // 0..3

  // ---- A streams (2 unique frags/wave), mid-anchored imm offsets ----
  const uint8_t* Abase =
      Ap + ((size_t)((bi & 31) * 16 + w * 2)) * 8192 + (size_t)lane * 16 + 3584;
  const uint8_t* aSt0 = Abase;
  const uint8_t* aSt1 = Abase + 8192;

  // A prefetch kbp=0,1
  PairU Ar[3][2];
#pragma unroll
  for (int p = 0; p < 2; p++) {
    const int ofs = p * 1024 - 3584;
    Ar[p][0].v = *(const int4*)(aSt0 + ofs);
    Ar[p][1].v = *(const int4*)(aSt1 + ofs);
  }

  // ---- B staging: linear 64KB copy (packed tile is contiguous) ----
  {
    const uint8_t* Bgp = Bp + (size_t)(bj & 63) * 65536;
#pragma unroll
    for (int rnd = 0; rnd < 8; rnd++)
      gload_lds16(Bgp + rnd * 8192 + t * 16, Bs + rnd * 8192 + t * 16);
  }

  f32x4 acc[2][8];
#pragma unroll
  for (int a = 0; a < 2; a++)
#pragma unroll
    for (int b = 0; b < 8; b++)
#pragma unroll
      for (int r = 0; r < 4; r++) acc[a][b][r] = 0.0f;

  const uint8_t* BsL = Bs + lane * 16;   // single VGPR base, all-imm offsets

  __syncthreads();   // B tile ready (also drains the A prefetch, fine)

  // B register double-buffer: load kbp=0 into Bbuf[0]
  PairU Bbuf[2][8];
#pragma unroll
  for (int f = 0; f < 8; f++)
    Bbuf[0][f].v = *(const int4*)(BsL + f * 8192);

#pragma unroll
  for (int kbp = 0; kbp < 8; kbp++) {
    const int cur = kbp % 3;
    const int bc = kbp & 1;
    if (kbp < 6) {
      const int nxt = (kbp + 2) % 3;
      const int ofs = (kbp + 2) * 1024 - 3584;
      Ar[nxt][0].v = *(const int4*)(aSt0 + ofs);
      Ar[nxt][1].v = *(const int4*)(aSt1 + ofs);
    }
    if (kbp < 7) {
#pragma unroll
      for (int f = 0; f < 8; f++)
        Bbuf[bc ^ 1][f].v = *(const int4*)(BsL + f * 8192 + (kbp + 1) * 1024);
    }
#pragma unroll
    for (int fm = 0; fm < 2; fm++)
#pragma unroll
      for (int fn = 0; fn < 8; fn++)
        acc[fm][fn] = __builtin_amdgcn_mfma_f32_16x16x32_fp8_fp8(
            Ar[cur][fm].s.lo, Bbuf[bc][fn].s.lo, acc[fm][fn], 0, 0, 0);
#pragma unroll
    for (int fm = 0; fm < 2; fm++)
#pragma unroll
      for (int fn = 0; fn < 8; fn++)
        acc[fm][fn] = __builtin_amdgcn_mfma_f32_16x16x32_fp8_fp8(
            Ar[cur][fm].s.hi, Bbuf[bc][fn].s.hi, acc[fm][fn], 0, 0, 0);
  }

  // ---- Epilogue. C/D layout: col = lane&15, row = kq*4+reg ----
  float rowp[2][4];
  float colp[8];
#pragma unroll
  for (int fm = 0; fm < 2; fm++)
#pragma unroll
    for (int r = 0; r < 4; r++) rowp[fm][r] = 0.0f;
#pragma unroll
  for (int fn = 0; fn < 8; fn++) colp[fn] = 0.0f;

  if (!needPred) {
#pragma unroll
    for (int fm = 0; fm < 2; fm++)
#pragma unroll
      for (int fn = 0; fn < 8; fn++)
#pragma unroll
        for (int r = 0; r < 4; r++) {
          const float e = __expf(acc[fm][fn][r] * INV_TAU);
          rowp[fm][r] += e;
          colp[fn] += e;
        }
  } else {
    // diagonal-straddling: keep rows gi<=gj, cols gi<gj (W-space indices)
#pragma unroll
    for (int fm = 0; fm < 2; fm++)
#pragma unroll
      for (int fn = 0; fn < 8; fn++)
#pragma unroll
        for (int r = 0; r < 4; r++) {
          const int gi = giBase + w * 32 + fm * 16 + kq * 4 + r;
          const int gj = gjBase + fn * 16 + l16;
          const float e = __expf(acc[fm][fn][r] * INV_TAU);
          rowp[fm][r] += (gi <= gj) ? e : 0.0f;
          colp[fn] += (gi < gj) ? e : 0.0f;
        }
  }

  // reduction buffers alias into Bs — safe after all waves left the K-loop
  __syncthreads();
  float* lds_col = (float*)Bs;          // 128 floats, contended -> zero+atomic
  float* lds_row = lds_col + 128;       // 256 floats, unique -> plain store
  if (t < 128) lds_col[t] = 0.0f;
  __syncthreads();

  // Row sums: reduce across the 16 lanes (cols) sharing kq; each (w,fm,kq,r)
  // index is owned by exactly one lane -> plain store.
#pragma unroll
  for (int fm = 0; fm < 2; fm++) {
#pragma unroll
    for (int r = 0; r < 4; r++) {
      float v = rowp[fm][r];
      v += __shfl_xor(v, 1);
      v += __shfl_xor(v, 2);
      v += __shfl_xor(v, 4);
      v += __shfl_xor(v, 8);
      if (l16 == 0) lds_row[w * 32 + fm * 16 + kq * 4 + r] = v;
    }
  }
  // Col sums: reduce across the 4 kq groups; 8 waves contend per col.
#pragma unroll
  for (int fn = 0; fn < 8; fn++) {
    float v = colp[fn];
    v += __shfl_xor(v, 16);
    v += __shfl_xor(v, 32);
    if (kq == 0) atomicAdd(&lds_col[fn * 16 + l16], v);
  }
  __syncthreads();

  if (t < 256) atomicAdd(&rowsOut[iOutBase + t], lds_row[t]);
  else if (t < 384) atomicAdd(&colsOut[jOutBase + (t - 256)], lds_col[t - 256]);
}

__global__ __launch_bounds__(256) void finalize_kernel(
    const float* __restrict__ r1, const float* __restrict__ r2,
    const float* __restrict__ brow, const float* __restrict__ bcol,
    const float* __restrict__ dvec, float* __restrict__ out) {
  const int i = blockIdx.x * 256 + threadIdx.x;
  const float den1 = r1[i] + brow[i] - EXP5;
  const float den2 = r2[i] + bcol[i] - EXP5;
  float v = 0.5f * (logf(den1) + logf(den2)) - INV_TAU * dvec[i];
  for (int m = 32; m; m >>= 1) v += __shfl_xor(v, m);
  __shared__ float red[4];
  const int wave = threadIdx.x >> 6;
  if ((threadIdx.x & 63) == 0) red[wave] = v;
  __syncthreads();
  if (threadIdx.x == 0) atomicAdd(out, red[0] + red[1] + red[2] + red[3]);
}

extern "C" void kernel_launch(void* const* d_in, const int* in_sizes, int n_in,
                              void* d_out, int out_size, void* d_ws, size_t ws_size,
                              hipStream_t stream) {
  const float* z1 = (const float*)d_in[0];
  const float* z2 = (const float*)d_in[1];
  float* out = (float*)d_out;

  char* ws = (char*)d_ws;
  uint8_t* h1p = (uint8_t*)ws;                 // 4 MiB fp8 pair-packed
  uint8_t* h2p = (uint8_t*)(ws + (4u << 20));  // 4 MiB
  float* r1   = (float*)(ws + (8u << 20));
  float* r2   = r1 + N_ROWS;
  float* brow = r2 + N_ROWS;
  float* bcol = brow + N_ROWS;
  float* dvec = bcol + N_ROWS;

  normalize_kernel<<<N_ROWS / 16, 256, 0, stream>>>(
      z1, z2, h1p, h2p, dvec, r1, r2, brow, bcol, out);
  expsum_kernel<<<4160, 512, 0, stream>>>(h1p, h2p, r1, r2, brow, bcol);
  finalize_kernel<<<N_ROWS / 256, 256, 0, stream>>>(r1, r2, brow, bcol, dvec, out);
}

// Round 14
// 200.076 us; speedup vs baseline: 1.0531x; 1.0395x over previous
//
#include <hip/hip_runtime.h>
#include <hip/hip_bf16.h>
#include <math.h>
#include <stdint.h>

#define N_ROWS 8192
#define DIM 512
#define INV_TAU 5.0f
#define EXP5 148.41315910257660342f   // exp(1/tau) = exp(5)

typedef float f32x4 __attribute__((ext_vector_type(4)));
typedef int   i32x4 __attribute__((ext_vector_type(4)));
typedef int   i32x8 __attribute__((ext_vector_type(8)));

union Frag8 {            // one K=128 fragment: 32 B/lane = 8 VGPRs
  i32x8 v8;
  struct { i32x4 lo, hi; } s;
};

__device__ __forceinline__ void gload_lds16(const void* g, void* l) {
  __builtin_amdgcn_global_load_lds(
      (__attribute__((address_space(1))) void*)(void*)g,
      (__attribute__((address_space(3))) void*)l,
      16, 0, 0);
}

// Block = 16 rows (one MFMA group), 256 threads. Thread t: row t>>4, k-span
// (t&15)*32..+31. Norms via 16-lane butterfly, fp32 diag dot, fp8 e4m3
// quantization into the K=128 MX-fragment packed layout:
//   unit (g=row/16, ks=k/128) = 2048 B, two lane-major halves:
//     h=0 @ +0   : lane l's bytes k=(l>>4)*32+ 0..15 (v[0:3])
//     h=1 @ +1024: lane l's bytes k=(l>>4)*32+16..31 (v[4:7])
//   lane l: row l&15. 8 KB per group per array. One frag = 2 int4 loads.
// Scatter goes through LDS so global writes are coalesced int4.
// Also zeroes r1/r2/brow/bcol/out.
__global__ __launch_bounds__(256) void normalize_kernel(
    const float* __restrict__ z1, const float* __restrict__ z2,
    uint8_t* __restrict__ h1p, uint8_t* __restrict__ h2p,
    float* __restrict__ dvec,
    float* __restrict__ r1, float* __restrict__ r2,
    float* __restrict__ brow, float* __restrict__ bcol,
    float* __restrict__ out) {
  __shared__ __align__(16) uint8_t L[16384];  // 8KB h1-part, 8KB h2-part
  const int t = threadIdx.x;
  const int lr = t >> 4;          // row in group 0..15
  const int kb = t & 15;          // this thread's 32-elem k-block
  const int row = blockIdx.x * 16 + lr;
  const float4* p1 = (const float4*)(z1 + (size_t)row * DIM + kb * 32);
  const float4* p2 = (const float4*)(z2 + (size_t)row * DIM + kb * 32);
  float4 a[8], b[8];
  float s1 = 0.f, s2 = 0.f, s3 = 0.f;
#pragma unroll
  for (int i = 0; i < 8; i++) {
    a[i] = p1[i]; b[i] = p2[i];
    s1 += a[i].x*a[i].x + a[i].y*a[i].y + a[i].z*a[i].z + a[i].w*a[i].w;
    s2 += b[i].x*b[i].x + b[i].y*b[i].y + b[i].z*b[i].z + b[i].w*b[i].w;
    s3 += a[i].x*b[i].x + a[i].y*b[i].y + a[i].z*b[i].z + a[i].w*b[i].w;
  }
  for (int m = 1; m <= 8; m <<= 1) {
    s1 += __shfl_xor(s1, m);
    s2 += __shfl_xor(s2, m);
    s3 += __shfl_xor(s3, m);
  }
  const float inv1 = 1.0f / fmaxf(sqrtf(s1), 1e-12f);
  const float inv2 = 1.0f / fmaxf(sqrtf(s2), 1e-12f);
  int w1[8], w2[8];
#pragma unroll
  for (int i = 0; i < 8; i++) {
    int w = __builtin_amdgcn_cvt_pk_fp8_f32(a[i].x*inv1, a[i].y*inv1, 0, false);
    w1[i] = __builtin_amdgcn_cvt_pk_fp8_f32(a[i].z*inv1, a[i].w*inv1, w, true);
    w = __builtin_amdgcn_cvt_pk_fp8_f32(b[i].x*inv2, b[i].y*inv2, 0, false);
    w2[i] = __builtin_amdgcn_cvt_pk_fp8_f32(b[i].z*inv2, b[i].w*inv2, w, true);
  }
  // K=128 packed LDS scatter: this k-block is unit ks=kb>>2, lane
  // l=(kb&3)*16+lr; first 16B -> h=0, last 16B -> h=1.
  const int ks = kb >> 2;
  const int l = (kb & 3) * 16 + lr;
  *(int4*)(L + ks * 2048 + l * 16)          = make_int4(w1[0], w1[1], w1[2], w1[3]);
  *(int4*)(L + ks * 2048 + 1024 + l * 16)   = make_int4(w1[4], w1[5], w1[6], w1[7]);
  *(int4*)(L + 8192 + ks * 2048 + l * 16)        = make_int4(w2[0], w2[1], w2[2], w2[3]);
  *(int4*)(L + 8192 + ks * 2048 + 1024 + l * 16) = make_int4(w2[4], w2[5], w2[6], w2[7]);
  if (kb == 0) dvec[row] = s3 * inv1 * inv2;
  if (t < 16) {
    const int i = blockIdx.x * 16 + t;
    r1[i] = 0.f; r2[i] = 0.f; brow[i] = 0.f; bcol[i] = 0.f;
    if (i == 0) out[0] = 0.f;
  }
  __syncthreads();
  const size_t gb = (size_t)blockIdx.x * 8192;
  int4* g1 = (int4*)(h1p + gb);
  int4* g2 = (int4*)(h2p + gb);
  const int4* Lv = (const int4*)L;
  g1[t]       = Lv[t];
  g1[t + 256] = Lv[t + 256];
  g2[t]       = Lv[t + 512];
  g2[t + 256] = Lv[t + 768];
}

// Upper triangle of W W^T, W=[h1;h2] (16384 rows), 128x128 tiles, 8256
// blocks (r7 decode), 256 threads / 4 waves; wave w owns rows 32w..32w+31
// (2 row-frags) x 128 cols (8 col-frags) using the MX-scaled
// v_mfma_scale_f32_16x16x128_f8f6f4 (scales = 1.0 -> bit-identical to the
// fp8 path, 2.2x the MFMA rate). ALL A fragments (8 Frag8 = 64 VGPR) are
// preloaded before the single staging barrier -> the K-loop (4 iterations:
// 16 ds_read_b128 + 16 MFMA) contains no VMEM at all. B tile = 64 KB LDS,
// staged once, conflict-free lane-major layout.
__global__ __launch_bounds__(256) void expsum_kernel(
    const uint8_t* __restrict__ h1p, const uint8_t* __restrict__ h2p,
    float* __restrict__ r1, float* __restrict__ r2,
    float* __restrict__ brow, float* __restrict__ bcol) {
  __shared__ __align__(16) uint8_t Bs[65536];   // 64 KB B tile

  const int u = (blockIdx.x & 7) * 1032 + (blockIdx.x >> 3);  // 8256 = 8*1032
  int bj = (int)((sqrt(8.0 * (double)u + 1.0) - 1.0) * 0.5);
  if (bj * (bj + 1) / 2 > u) bj--;
  if ((bj + 1) * (bj + 2) / 2 <= u) bj++;
  const int bi = u - bj * (bj + 1) / 2;
  const bool diagb = (bi == bj);

  const uint8_t* Ap = (bi < 64) ? h1p : h2p;
  const uint8_t* Bp = (bj < 64) ? h1p : h2p;
  float* rowsOut = (bi < 64) ? ((bj < 64) ? r1 : brow) : r2;
  float* colsOut = (bj < 64) ? r1 : ((bi < 64) ? bcol : r2);
  const int iOutBase = (bi & 63) * 128;
  const int jOutBase = (bj & 63) * 128;

  const int t = threadIdx.x;
  const int w = t >> 6;         // wave 0..3: rows 32w..32w+31
  const int lane = t & 63;
  const int l16 = lane & 15;
  const int kq = lane >> 4;     // 0..3

  // ---- A: preload ALL fragments (2 row-groups x 4 ks), mid-anchored ----
  const uint8_t* Ag =
      Ap + ((size_t)((bi & 63) * 8 + w * 2)) * 8192 + (size_t)lane * 16 + 4096;
  Frag8 Af[2][4];
#pragma unroll
  for (int f = 0; f < 2; f++)
#pragma unroll
    for (int ks = 0; ks < 4; ks++) {
      const int ofs = f * 8192 + ks * 2048 - 4096;
      Af[f][ks].s.lo = *(const i32x4*)(Ag + ofs);
      Af[f][ks].s.hi = *(const i32x4*)(Ag + ofs + 1024);
    }

  // ---- B staging: linear 64KB copy (packed tile is contiguous) ----
  {
    const uint8_t* Bgp = Bp + (size_t)(bj & 63) * 65536;
#pragma unroll
    for (int rnd = 0; rnd < 16; rnd++)
      gload_lds16(Bgp + rnd * 4096 + t * 16, Bs + rnd * 4096 + t * 16);
  }

  f32x4 acc[2][8];
#pragma unroll
  for (int a = 0; a < 2; a++)
#pragma unroll
    for (int b = 0; b < 8; b++)
#pragma unroll
      for (int r = 0; r < 4; r++) acc[a][b][r] = 0.0f;

  const uint8_t* BsL = Bs + lane * 16;   // single VGPR base, all-imm offsets

  __syncthreads();   // B tile ready (also drains the A preload, fine)

#pragma unroll
  for (int ks = 0; ks < 4; ks++) {
    Frag8 Bf[8];
#pragma unroll
    for (int fn = 0; fn < 8; fn++) {
      Bf[fn].s.lo = *(const i32x4*)(BsL + fn * 8192 + ks * 2048);
      Bf[fn].s.hi = *(const i32x4*)(BsL + fn * 8192 + ks * 2048 + 1024);
    }
#pragma unroll
    for (int fm = 0; fm < 2; fm++)
#pragma unroll
      for (int fn = 0; fn < 8; fn++)
        acc[fm][fn] = __builtin_amdgcn_mfma_scale_f32_16x16x128_f8f6f4(
            Af[fm][ks].v8, Bf[fn].v8, acc[fm][fn],
            0, 0,                    // fmt A = fp8(e4m3), fmt B = fp8(e4m3)
            0, 0x7F7F7F7F,           // scale A: e8m0 127 -> 1.0
            0, 0x7F7F7F7F);          // scale B: 1.0
  }

  // ---- Epilogue. C/D layout (shape-determined): col=lane&15, row=kq*4+reg ----
  float rowp[2][4];
  float colp[8];
#pragma unroll
  for (int fm = 0; fm < 2; fm++)
#pragma unroll
    for (int r = 0; r < 4; r++) rowp[fm][r] = 0.0f;
#pragma unroll
  for (int fn = 0; fn < 8; fn++) colp[fn] = 0.0f;

  if (!diagb) {
#pragma unroll
    for (int fm = 0; fm < 2; fm++)
#pragma unroll
      for (int fn = 0; fn < 8; fn++)
#pragma unroll
        for (int r = 0; r < 4; r++) {
          const float e = __expf(acc[fm][fn][r] * INV_TAU);
          rowp[fm][r] += e;
          colp[fn] += e;
        }
  } else {
    // within-tile indices (i0==j0): rows keep ti<=tj, cols keep ti<tj
#pragma unroll
    for (int fm = 0; fm < 2; fm++)
#pragma unroll
      for (int fn = 0; fn < 8; fn++)
#pragma unroll
        for (int r = 0; r < 4; r++) {
          const int ti = w * 32 + fm * 16 + kq * 4 + r;
          const int tj = fn * 16 + l16;
          const float e = __expf(acc[fm][fn][r] * INV_TAU);
          rowp[fm][r] += (ti <= tj) ? e : 0.0f;
          colp[fn] += (ti < tj) ? e : 0.0f;
        }
  }

  // reduction buffers alias into Bs — safe after all waves left the K-loop
  __syncthreads();
  float* lds_col = (float*)Bs;          // 128 floats, contended -> zero+atomic
  float* lds_row = lds_col + 128;       // 128 floats, unique -> plain store
  if (t < 128) lds_col[t] = 0.0f;
  __syncthreads();

  // Row sums: reduce across the 16 lanes (cols) sharing kq; unique dest per
  // (w,fm,kq,r) -> plain store.
#pragma unroll
  for (int fm = 0; fm < 2; fm++) {
#pragma unroll
    for (int r = 0; r < 4; r++) {
      float v = rowp[fm][r];
      v += __shfl_xor(v, 1);
      v += __shfl_xor(v, 2);
      v += __shfl_xor(v, 4);
      v += __shfl_xor(v, 8);
      if (l16 == 0) lds_row[w * 32 + fm * 16 + kq * 4 + r] = v;
    }
  }
  // Col sums: reduce across the 4 kq groups; 4 waves contend per col.
#pragma unroll
  for (int fn = 0; fn < 8; fn++) {
    float v = colp[fn];
    v += __shfl_xor(v, 16);
    v += __shfl_xor(v, 32);
    if (kq == 0) atomicAdd(&lds_col[fn * 16 + l16], v);
  }
  __syncthreads();

  if (t < 128) atomicAdd(&rowsOut[iOutBase + t], lds_row[t]);
  else         atomicAdd(&colsOut[jOutBase + (t - 128)], lds_col[t - 128]);
}

__global__ __launch_bounds__(256) void finalize_kernel(
    const float* __restrict__ r1, const float* __restrict__ r2,
    const float* __restrict__ brow, const float* __restrict__ bcol,
    const float* __restrict__ dvec, float* __restrict__ out) {
  const int i = blockIdx.x * 256 + threadIdx.x;
  const float den1 = r1[i] + brow[i] - EXP5;
  const float den2 = r2[i] + bcol[i] - EXP5;
  float v = 0.5f * (logf(den1) + logf(den2)) - INV_TAU * dvec[i];
  for (int m = 32; m; m >>= 1) v += __shfl_xor(v, m);
  __shared__ float red[4];
  const int wave = threadIdx.x >> 6;
  if ((threadIdx.x & 63) == 0) red[wave] = v;
  __syncthreads();
  if (threadIdx.x == 0) atomicAdd(out, red[0] + red[1] + red[2] + red[3]);
}

extern "C" void kernel_launch(void* const* d_in, const int* in_sizes, int n_in,
                              void* d_out, int out_size, void* d_ws, size_t ws_size,
                              hipStream_t stream) {
  const float* z1 = (const float*)d_in[0];
  const float* z2 = (const float*)d_in[1];
  float* out = (float*)d_out;

  char* ws = (char*)d_ws;
  uint8_t* h1p = (uint8_t*)ws;                 // 4 MiB fp8 K128-packed
  uint8_t* h2p = (uint8_t*)(ws + (4u << 20));  // 4 MiB
  float* r1   = (float*)(ws + (8u << 20));
  float* r2   = r1 + N_ROWS;
  float* brow = r2 + N_ROWS;
  float* bcol = brow + N_ROWS;
  float* dvec = bcol + N_ROWS;

  normalize_kernel<<<N_ROWS / 16, 256, 0, stream>>>(
      z1, z2, h1p, h2p, dvec, r1, r2, brow, bcol, out);
  expsum_kernel<<<8256, 256, 0, stream>>>(h1p, h2p, r1, r2, brow, bcol);
  finalize_kernel<<<N_ROWS / 256, 256, 0, stream>>>(r1, r2, brow, bcol, dvec, out);
}